// Round 3
// baseline (1383.852 us; speedup 1.0000x reference)
//
#include <hip/hip_runtime.h>

typedef unsigned short ushort_t;
typedef __bf16 bf16x8_t __attribute__((ext_vector_type(8)));
typedef float f32x4_t __attribute__((ext_vector_type(4)));

#define AS1(p) ((const __attribute__((address_space(1))) void*)(p))
#define AS3(p) ((__attribute__((address_space(3))) void*)(p))
#define DEVINL __device__ __forceinline__

DEVINL ushort_t f2bf(float f) {
    unsigned int u = __builtin_bit_cast(unsigned int, f);
    u += 0x7fffu + ((u >> 16) & 1u);
    return (ushort_t)(u >> 16);
}
DEVINL float bf2f(ushort_t h) {
    unsigned int u = ((unsigned int)h) << 16;
    return __builtin_bit_cast(float, u);
}

DEVINL float warp_sum(float v) {
#pragma unroll
    for (int o = 32; o > 0; o >>= 1) v += __shfl_xor(v, o);
    return v;
}
DEVINL float warp_max(float v) {
#pragma unroll
    for (int o = 32; o > 0; o >>= 1) v = fmaxf(v, __shfl_xor(v, o));
    return v;
}
DEVINL float block_sum(float v, float* sb) {
    v = warp_sum(v);
    int w = threadIdx.x >> 6;
    if ((threadIdx.x & 63) == 0) sb[w] = v;
    __syncthreads();
    v = sb[0] + sb[1] + sb[2] + sb[3];
    __syncthreads();
    return v;
}
DEVINL float block_max(float v, float* sb) {
    v = warp_max(v);
    int w = threadIdx.x >> 6;
    if ((threadIdx.x & 63) == 0) sb[w] = v;
    __syncthreads();
    v = fmaxf(fmaxf(sb[0], sb[1]), fmaxf(sb[2], sb[3]));
    __syncthreads();
    return v;
}

// ---------------------------------------------------------------------------
// NT GEMM: C[m,n] = sum_k A[m,k]*B[n,k], 128x128 tile, BK=32.
// EPI: 0 = fp32 out (+bias, +optional accumulate), 1 = bf16 (+bias),
//      2 = bf16 relu (+bias).
// ---------------------------------------------------------------------------
template <int EPI>
__global__ __launch_bounds__(256) void gemm_bt(
    const ushort_t* __restrict__ A, long lda, long sA1, long sA2,
    const ushort_t* __restrict__ B, long ldb, long sB1, long sB2,
    void* __restrict__ Cp, long ldc, long sC1, long sC2,
    const float* __restrict__ bias, int accum, int K, int batch2)
{
    __shared__ __align__(16) __bf16 As[128 * 32];
    __shared__ __align__(16) __bf16 Bs[128 * 32];

    const int tid = threadIdx.x;
    const int lane = tid & 63;
    const int wave = tid >> 6;
    const int wm = wave >> 1, wn = wave & 1;
    const int quad = lane >> 4, l16 = lane & 15;
    const long m0 = (long)blockIdx.y * 128;
    const long n0 = (long)blockIdx.x * 128;
    const int z = blockIdx.z;
    const int z1 = z / batch2, z2 = z % batch2;
    A += (long)z1 * sA1 + (long)z2 * sA2;
    B += (long)z1 * sB1 + (long)z2 * sB2;

    f32x4_t acc[4][4];
#pragma unroll
    for (int i = 0; i < 4; i++)
#pragma unroll
        for (int j = 0; j < 4; j++) {
            f32x4_t zv = {0.f, 0.f, 0.f, 0.f};
            acc[i][j] = zv;
        }

    const int ea = tid * 8;
    const int nkt = K >> 5;
    for (int kt = 0; kt < nkt; ++kt) {
        const int k0 = kt << 5;
#pragma unroll
        for (int inst = 0; inst < 2; ++inst) {
            int e = ea + inst * 2048;
            int row = e >> 5, kk = e & 31;
            __builtin_amdgcn_global_load_lds(AS1(A + (m0 + row) * lda + k0 + kk), AS3(As + e), 16, 0, 0);
            __builtin_amdgcn_global_load_lds(AS1(B + (n0 + row) * ldb + k0 + kk), AS3(Bs + e), 16, 0, 0);
        }
        __syncthreads();
        bf16x8_t af[4], bfr[4];
#pragma unroll
        for (int i = 0; i < 4; i++)
            af[i] = *(const bf16x8_t*)(As + (wm * 64 + i * 16 + l16) * 32 + quad * 8);
#pragma unroll
        for (int j = 0; j < 4; j++)
            bfr[j] = *(const bf16x8_t*)(Bs + (wn * 64 + j * 16 + l16) * 32 + quad * 8);
#pragma unroll
        for (int i = 0; i < 4; i++)
#pragma unroll
            for (int j = 0; j < 4; j++)
                acc[i][j] = __builtin_amdgcn_mfma_f32_16x16x32_bf16(af[i], bfr[j], acc[i][j], 0, 0, 0);
        __syncthreads();
    }

    if constexpr (EPI == 0) {
        float* C = (float*)Cp + (long)z1 * sC1 + (long)z2 * sC2;
#pragma unroll
        for (int i = 0; i < 4; i++)
#pragma unroll
            for (int reg = 0; reg < 4; reg++) {
                long row = m0 + wm * 64 + i * 16 + quad * 4 + reg;
#pragma unroll
                for (int j = 0; j < 4; j++) {
                    long col = n0 + wn * 64 + j * 16 + l16;
                    float v = acc[i][j][reg];
                    if (bias) v += bias[col];
                    long idx = row * ldc + col;
                    if (accum) v += C[idx];
                    C[idx] = v;
                }
            }
    } else {
        ushort_t* C = (ushort_t*)Cp + (long)z1 * sC1 + (long)z2 * sC2;
#pragma unroll
        for (int i = 0; i < 4; i++)
#pragma unroll
            for (int reg = 0; reg < 4; reg++) {
                long row = m0 + wm * 64 + i * 16 + quad * 4 + reg;
#pragma unroll
                for (int j = 0; j < 4; j++) {
                    long col = n0 + wn * 64 + j * 16 + l16;
                    float v = acc[i][j][reg];
                    if (bias) v += bias[col];
                    if constexpr (EPI == 2) v = fmaxf(v, 0.f);
                    C[row * ldc + col] = f2bf(v);
                }
            }
    }
}

// ---------------------------------------------------------------------------
// Split-precision NT GEMM (bf16x2): C = (Ah+Al)*(Bh+Bl)^T ~ AhBh + AhBl + AlBh
// fp32 out + bias. 128x128 tile.
// ---------------------------------------------------------------------------
__global__ __launch_bounds__(256) void gemm_split(
    const ushort_t* __restrict__ Ah, const ushort_t* __restrict__ Al, long lda,
    const ushort_t* __restrict__ Bh, const ushort_t* __restrict__ Bl, long ldb,
    float* __restrict__ C, long ldc, const float* __restrict__ bias, int K)
{
    __shared__ __align__(16) __bf16 Ahs[4096], Als[4096], Bhs[4096], Bls[4096];
    const int tid = threadIdx.x;
    const int lane = tid & 63;
    const int wave = tid >> 6;
    const int wm = wave >> 1, wn = wave & 1;
    const int quad = lane >> 4, l16 = lane & 15;
    const long m0 = (long)blockIdx.y * 128;
    const long n0 = (long)blockIdx.x * 128;

    f32x4_t acc[4][4];
#pragma unroll
    for (int i = 0; i < 4; i++)
#pragma unroll
        for (int j = 0; j < 4; j++) {
            f32x4_t zv = {0.f, 0.f, 0.f, 0.f};
            acc[i][j] = zv;
        }

    const int ea = tid * 8;
    const int nkt = K >> 5;
    for (int kt = 0; kt < nkt; ++kt) {
        const int k0 = kt << 5;
#pragma unroll
        for (int inst = 0; inst < 2; ++inst) {
            int e = ea + inst * 2048;
            int row = e >> 5, kk = e & 31;
            long ao = (m0 + row) * lda + k0 + kk;
            long bo = (n0 + row) * ldb + k0 + kk;
            __builtin_amdgcn_global_load_lds(AS1(Ah + ao), AS3(Ahs + e), 16, 0, 0);
            __builtin_amdgcn_global_load_lds(AS1(Al + ao), AS3(Als + e), 16, 0, 0);
            __builtin_amdgcn_global_load_lds(AS1(Bh + bo), AS3(Bhs + e), 16, 0, 0);
            __builtin_amdgcn_global_load_lds(AS1(Bl + bo), AS3(Bls + e), 16, 0, 0);
        }
        __syncthreads();
        bf16x8_t ah[4], al[4], bh[4], bl[4];
#pragma unroll
        for (int i = 0; i < 4; i++) {
            int off = (wm * 64 + i * 16 + l16) * 32 + quad * 8;
            ah[i] = *(const bf16x8_t*)(Ahs + off);
            al[i] = *(const bf16x8_t*)(Als + off);
        }
#pragma unroll
        for (int j = 0; j < 4; j++) {
            int off = (wn * 64 + j * 16 + l16) * 32 + quad * 8;
            bh[j] = *(const bf16x8_t*)(Bhs + off);
            bl[j] = *(const bf16x8_t*)(Bls + off);
        }
#pragma unroll
        for (int i = 0; i < 4; i++)
#pragma unroll
            for (int j = 0; j < 4; j++) {
                acc[i][j] = __builtin_amdgcn_mfma_f32_16x16x32_bf16(al[i], bh[j], acc[i][j], 0, 0, 0);
                acc[i][j] = __builtin_amdgcn_mfma_f32_16x16x32_bf16(ah[i], bl[j], acc[i][j], 0, 0, 0);
                acc[i][j] = __builtin_amdgcn_mfma_f32_16x16x32_bf16(ah[i], bh[j], acc[i][j], 0, 0, 0);
            }
        __syncthreads();
    }

#pragma unroll
    for (int i = 0; i < 4; i++)
#pragma unroll
        for (int reg = 0; reg < 4; reg++) {
            long row = m0 + wm * 64 + i * 16 + quad * 4 + reg;
#pragma unroll
            for (int j = 0; j < 4; j++) {
                long col = n0 + wn * 64 + j * 16 + l16;
                C[row * ldc + col] = acc[i][j][reg] + bias[col];
            }
        }
}

// ---------------------------------------------------------------------------
// Decoder CE GEMM: 256x128 tile (A = activations 256 rows, B = dec_W 128 rows).
// Each wave: 64 rows x 128 cols (acc[4][8]). Epilogue: per-(row, 128-col)
// partial max/sumexp + label-logit capture; labels computed inline.
// ---------------------------------------------------------------------------
__global__ __launch_bounds__(256) void gemm_ce(
    const ushort_t* __restrict__ A, long lda,
    const ushort_t* __restrict__ B, long ldb,
    int K, int n_real, const int* __restrict__ inputs,
    float* __restrict__ part_m, float* __restrict__ part_s,
    float* __restrict__ label_logit)
{
    __shared__ __align__(16) __bf16 As[256 * 32];
    __shared__ __align__(16) __bf16 Bs[128 * 32];

    const int tid = threadIdx.x;
    const int lane = tid & 63;
    const int wave = tid >> 6;
    const int quad = lane >> 4, l16 = lane & 15;
    const long m0 = (long)blockIdx.y * 256;
    const long n0 = (long)blockIdx.x * 128;

    f32x4_t acc[4][8];
#pragma unroll
    for (int i = 0; i < 4; i++)
#pragma unroll
        for (int j = 0; j < 8; j++) {
            f32x4_t zv = {0.f, 0.f, 0.f, 0.f};
            acc[i][j] = zv;
        }

    const int ea = tid * 8;
    const int nkt = K >> 5;
    for (int kt = 0; kt < nkt; ++kt) {
        const int k0 = kt << 5;
#pragma unroll
        for (int inst = 0; inst < 4; ++inst) {
            int e = ea + inst * 2048;
            int row = e >> 5, kk = e & 31;
            __builtin_amdgcn_global_load_lds(AS1(A + (m0 + row) * lda + k0 + kk), AS3(As + e), 16, 0, 0);
        }
#pragma unroll
        for (int inst = 0; inst < 2; ++inst) {
            int e = ea + inst * 2048;
            int row = e >> 5, kk = e & 31;
            __builtin_amdgcn_global_load_lds(AS1(B + (n0 + row) * ldb + k0 + kk), AS3(Bs + e), 16, 0, 0);
        }
        __syncthreads();
        bf16x8_t af[4], bfr[8];
#pragma unroll
        for (int i = 0; i < 4; i++)
            af[i] = *(const bf16x8_t*)(As + (wave * 64 + i * 16 + l16) * 32 + quad * 8);
#pragma unroll
        for (int j = 0; j < 8; j++)
            bfr[j] = *(const bf16x8_t*)(Bs + (j * 16 + l16) * 32 + quad * 8);
#pragma unroll
        for (int i = 0; i < 4; i++)
#pragma unroll
            for (int j = 0; j < 8; j++)
                acc[i][j] = __builtin_amdgcn_mfma_f32_16x16x32_bf16(af[i], bfr[j], acc[i][j], 0, 0, 0);
        __syncthreads();
    }

#pragma unroll
    for (int i = 0; i < 4; i++) {
#pragma unroll
        for (int reg = 0; reg < 4; reg++) {
            long row = m0 + wave * 64 + i * 16 + quad * 4 + reg;
            int lab = ((row & 255) == 255) ? -1 : inputs[row + 1];
            float mx = -INFINITY;
#pragma unroll
            for (int j = 0; j < 8; j++) {
                long col = n0 + j * 16 + l16;
                float v = acc[i][j][reg];
                if (col < n_real) mx = fmaxf(mx, v);
            }
#pragma unroll
            for (int o = 8; o > 0; o >>= 1) mx = fmaxf(mx, __shfl_xor(mx, o));
            float sm = 0.f;
#pragma unroll
            for (int j = 0; j < 8; j++) {
                long col = n0 + j * 16 + l16;
                float v = acc[i][j][reg];
                if (col < n_real) sm += __expf(v - mx);
                if (col == lab) label_logit[row] = v;
            }
#pragma unroll
            for (int o = 8; o > 0; o >>= 1) sm += __shfl_xor(sm, o);
            if (l16 == 0) {
                long pidx = row * 393 + blockIdx.x;
                part_m[pidx] = mx;
                part_s[pidx] = sm;
            }
        }
    }
}

// ------------------------- small kernels -----------------------------------

// one fused convert: 5 segments of fp32 -> bf16
__global__ __launch_bounds__(256) void k_convert_seg(
    const float* __restrict__ s0, ushort_t* __restrict__ d0, long n0,
    const float* __restrict__ s1, ushort_t* __restrict__ d1, long n1,
    const float* __restrict__ s2, ushort_t* __restrict__ d2, long n2,
    const float* __restrict__ s3, ushort_t* __restrict__ d3, long n3,
    const float* __restrict__ s4, ushort_t* __restrict__ d4, long n4)
{
    long i = ((long)blockIdx.x * 256 + threadIdx.x) * 4;
    const float* src; ushort_t* dst;
    if (i < n0) { src = s0; dst = d0; }
    else if ((i -= n0) < n1) { src = s1; dst = d1; }
    else if ((i -= n1) < n2) { src = s2; dst = d2; }
    else if ((i -= n2) < n3) { src = s3; dst = d3; }
    else if ((i -= n3) < n4) { src = s4; dst = d4; }
    else return;
    float4 v = *(const float4*)(src + i);
    dst[i + 0] = f2bf(v.x); dst[i + 1] = f2bf(v.y);
    dst[i + 2] = f2bf(v.z); dst[i + 3] = f2bf(v.w);
}

__global__ __launch_bounds__(256) void k_convert_pad(const float* __restrict__ src,
                                                     ushort_t* __restrict__ dst,
                                                     long n_src, long n_dst) {
    long i = ((long)blockIdx.x * 256 + threadIdx.x) * 4;
    if (i >= n_dst) return;
    if (i < n_src) {
        float4 v = *(const float4*)(src + i);
        dst[i + 0] = f2bf(v.x); dst[i + 1] = f2bf(v.y);
        dst[i + 2] = f2bf(v.z); dst[i + 3] = f2bf(v.w);
    } else {
        dst[i + 0] = 0; dst[i + 1] = 0; dst[i + 2] = 0; dst[i + 3] = 0;
    }
}

__global__ __launch_bounds__(256) void k_convert2(const float* __restrict__ src,
                                                  ushort_t* __restrict__ hi,
                                                  ushort_t* __restrict__ lo, long n) {
    long i = ((long)blockIdx.x * 256 + threadIdx.x) * 4;
    if (i >= n) return;
    float4 v = *(const float4*)(src + i);
    float vv[4] = {v.x, v.y, v.z, v.w};
#pragma unroll
    for (int j = 0; j < 4; j++) {
        ushort_t h = f2bf(vv[j]);
        hi[i + j] = h;
        lo[i + j] = f2bf(vv[j] - bf2f(h));
    }
}

__global__ __launch_bounds__(256) void k_gather2(const int* __restrict__ inputs,
                                                 const float* __restrict__ emb,
                                                 ushort_t* __restrict__ hi,
                                                 ushort_t* __restrict__ lo,
                                                 float* __restrict__ loss_out) {
    int t = blockIdx.x, tid = threadIdx.x;
    if (t == 0 && tid == 0) loss_out[0] = 0.f;
    long row = inputs[t];
    float4 v = *(const float4*)(emb + row * 1024 + tid * 4);
    long base = (long)t * 1024 + tid * 4;
    float vv[4] = {v.x, v.y, v.z, v.w};
#pragma unroll
    for (int j = 0; j < 4; j++) {
        ushort_t h = f2bf(vv[j]);
        hi[base + j] = h;
        lo[base + j] = f2bf(vv[j] - bf2f(h));
    }
}

// exact fp32 Q projection for the 4 last-position tokens: one wave per dim
__global__ __launch_bounds__(256) void k_rq(
    const int* __restrict__ inputs, const float* __restrict__ emb,
    const float* __restrict__ Wq, const float* __restrict__ bq,
    float* __restrict__ qf)
{
    __shared__ __align__(16) float xs[4096];
    int tid = threadIdx.x;
#pragma unroll
    for (int b2 = 0; b2 < 4; b2++) {
        long tok = inputs[b2 * 256 + 255];
        *(float4*)(xs + b2 * 1024 + tid * 4) = *(const float4*)(emb + tok * 1024 + tid * 4);
    }
    __syncthreads();
    int wave = tid >> 6, lane = tid & 63;
    int d = blockIdx.x * 4 + wave;
    const float4* wr = (const float4*)(Wq + (long)d * 1024) + lane * 4;
    const float4* x0 = (const float4*)xs + lane * 4;
    const float4* x1 = (const float4*)(xs + 1024) + lane * 4;
    const float4* x2 = (const float4*)(xs + 2048) + lane * 4;
    const float4* x3 = (const float4*)(xs + 3072) + lane * 4;
    float a0 = 0, a1 = 0, a2 = 0, a3 = 0;
#pragma unroll
    for (int k = 0; k < 4; k++) {
        float4 w = wr[k];
        float4 v0 = x0[k], v1 = x1[k], v2 = x2[k], v3 = x3[k];
        a0 += w.x * v0.x + w.y * v0.y + w.z * v0.z + w.w * v0.w;
        a1 += w.x * v1.x + w.y * v1.y + w.z * v1.z + w.w * v1.w;
        a2 += w.x * v2.x + w.y * v2.y + w.z * v2.z + w.w * v2.w;
        a3 += w.x * v3.x + w.y * v3.y + w.z * v3.z + w.w * v3.w;
    }
    a0 = warp_sum(a0); a1 = warp_sum(a1); a2 = warp_sum(a2); a3 = warp_sum(a3);
    if (lane < 4) {
        float a = (lane == 0) ? a0 : (lane == 1) ? a1 : (lane == 2) ? a2 : a3;
        qf[lane * 1024 + d] = a + bq[d];
    }
}

// routing attention, last query only; kv layout [B*S, 2048] (k | v)
__global__ __launch_bounds__(256) void k_rattn(const float* __restrict__ qf,
                                               const float* __restrict__ kv,
                                               float* __restrict__ o_rt) {
    int zz = blockIdx.x, b = zz >> 3, h = zz & 7, tid = threadIdx.x;
    __shared__ __align__(16) float q[128];
    __shared__ float p[256];
    __shared__ float sb[8];
    if (tid < 128) q[tid] = qf[b * 1024 + h * 128 + tid];
    __syncthreads();
    const float4* q4 = (const float4*)q;
    const float4* kr = (const float4*)(kv + ((long)(b * 256 + tid)) * 2048 + h * 128);
    float a = 0.f;
#pragma unroll 8
    for (int k = 0; k < 32; k++) {
        float4 wv = kr[k], xv = q4[k];
        a += wv.x * xv.x + wv.y * xv.y + wv.z * xv.z + wv.w * xv.w;
    }
    a *= 0.08838834764831845f;
    float m = block_max(a, sb);
    float e = __expf(a - m);
    float ssum = block_sum(e, sb);
    p[tid] = e / ssum;
    __syncthreads();
    if (tid < 128) {
        float acc = 0.f;
        const float* vb = kv + (long)b * 256 * 2048 + 1024 + h * 128 + tid;
        for (int s = 0; s < 256; s++) acc += p[s] * vb[(long)s * 2048];
        o_rt[b * 1024 + h * 128 + tid] = acc;
    }
}

// r[b][d] = emb[tok_b][d] + bo[d] + dot(Wo[d,:], o_rt[b,:])
__global__ __launch_bounds__(256) void k_rwo(
    const float* __restrict__ o_rt, const int* __restrict__ inputs,
    const float* __restrict__ emb, const float* __restrict__ Wo,
    const float* __restrict__ bo, float* __restrict__ rbuf)
{
    __shared__ __align__(16) float xs[4096];
    int tid = threadIdx.x;
#pragma unroll
    for (int i = 0; i < 16; i++) xs[i * 256 + tid] = o_rt[i * 256 + tid];
    __syncthreads();
    int wave = tid >> 6, lane = tid & 63;
    int d = blockIdx.x * 4 + wave;
    const float4* wr = (const float4*)(Wo + (long)d * 1024) + lane * 4;
    const float4* x0 = (const float4*)xs + lane * 4;
    const float4* x1 = (const float4*)(xs + 1024) + lane * 4;
    const float4* x2 = (const float4*)(xs + 2048) + lane * 4;
    const float4* x3 = (const float4*)(xs + 3072) + lane * 4;
    float a0 = 0, a1 = 0, a2 = 0, a3 = 0;
#pragma unroll
    for (int k = 0; k < 4; k++) {
        float4 w = wr[k];
        float4 v0 = x0[k], v1 = x1[k], v2 = x2[k], v3 = x3[k];
        a0 += w.x * v0.x + w.y * v0.y + w.z * v0.z + w.w * v0.w;
        a1 += w.x * v1.x + w.y * v1.y + w.z * v1.z + w.w * v1.w;
        a2 += w.x * v2.x + w.y * v2.y + w.z * v2.z + w.w * v2.w;
        a3 += w.x * v3.x + w.y * v3.y + w.z * v3.z + w.w * v3.w;
    }
    a0 = warp_sum(a0); a1 = warp_sum(a1); a2 = warp_sum(a2); a3 = warp_sum(a3);
    if (lane < 4) {
        float a = (lane == 0) ? a0 : (lane == 1) ? a1 : (lane == 2) ? a2 : a3;
        long tok = inputs[lane * 256 + 255];
        rbuf[lane * 1024 + d] = emb[tok * 1024 + d] + bo[d] + a;
    }
}

__global__ __launch_bounds__(256) void k_rln(const float* __restrict__ r,
                                             const float* __restrict__ g,
                                             const float* __restrict__ be,
                                             float* __restrict__ outp, float scale) {
    int row = blockIdx.x, tid = threadIdx.x;
    __shared__ float sb[8];
    const float* rr = r + (long)row * 1024;
    float v[4], s = 0.f, sq = 0.f;
#pragma unroll
    for (int i = 0; i < 4; i++) {
        v[i] = rr[i * 256 + tid];
        s += v[i]; sq += v[i] * v[i];
    }
    s = block_sum(s, sb); sq = block_sum(sq, sb + 4);
    float mean = s * (1.f / 1024.f);
    float rstd = rsqrtf(sq * (1.f / 1024.f) - mean * mean + 1e-5f);
#pragma unroll
    for (int i = 0; i < 4; i++) {
        int d = i * 256 + tid;
        outp[(long)row * 1024 + d] = ((v[i] - mean) * rstd * g[d] + be[d]) * scale;
    }
}

__global__ __launch_bounds__(256) void k_rff1(
    const float* __restrict__ x1f, const float* __restrict__ W1,
    const float* __restrict__ b1, float* __restrict__ f1f)
{
    __shared__ __align__(16) float xs[4096];
    int tid = threadIdx.x;
#pragma unroll
    for (int i = 0; i < 16; i++) xs[i * 256 + tid] = x1f[i * 256 + tid];
    __syncthreads();
    int wave = tid >> 6, lane = tid & 63;
    int j = blockIdx.x * 4 + wave;
    const float4* wr = (const float4*)(W1 + (long)j * 1024) + lane * 4;
    const float4* x0 = (const float4*)xs + lane * 4;
    const float4* x1 = (const float4*)(xs + 1024) + lane * 4;
    const float4* x2 = (const float4*)(xs + 2048) + lane * 4;
    const float4* x3 = (const float4*)(xs + 3072) + lane * 4;
    float a0 = 0, a1 = 0, a2 = 0, a3 = 0;
#pragma unroll
    for (int k = 0; k < 4; k++) {
        float4 w = wr[k];
        float4 v0 = x0[k], v1 = x1[k], v2 = x2[k], v3 = x3[k];
        a0 += w.x * v0.x + w.y * v0.y + w.z * v0.z + w.w * v0.w;
        a1 += w.x * v1.x + w.y * v1.y + w.z * v1.z + w.w * v1.w;
        a2 += w.x * v2.x + w.y * v2.y + w.z * v2.z + w.w * v2.w;
        a3 += w.x * v3.x + w.y * v3.y + w.z * v3.z + w.w * v3.w;
    }
    a0 = warp_sum(a0); a1 = warp_sum(a1); a2 = warp_sum(a2); a3 = warp_sum(a3);
    if (lane < 4) {
        float a = (lane == 0) ? a0 : (lane == 1) ? a1 : (lane == 2) ? a2 : a3;
        f1f[lane * 2048 + j] = fmaxf(b1[j] + a, 0.f);
    }
}

__global__ __launch_bounds__(256) void k_rff2(
    const float* __restrict__ f1f, const float* __restrict__ x1f,
    const float* __restrict__ W2, const float* __restrict__ b2,
    float* __restrict__ r2f)
{
    __shared__ __align__(16) float xs[8192];
    int tid = threadIdx.x;
#pragma unroll
    for (int i = 0; i < 32; i++) xs[i * 256 + tid] = f1f[i * 256 + tid];
    __syncthreads();
    int wave = tid >> 6, lane = tid & 63;
    int d = blockIdx.x * 4 + wave;
    const float4* wr = (const float4*)(W2 + (long)d * 2048) + lane * 8;
    const float4* x0 = (const float4*)xs + lane * 8;
    const float4* x1 = (const float4*)(xs + 2048) + lane * 8;
    const float4* x2 = (const float4*)(xs + 4096) + lane * 8;
    const float4* x3 = (const float4*)(xs + 6144) + lane * 8;
    float a0 = 0, a1 = 0, a2 = 0, a3 = 0;
#pragma unroll
    for (int k = 0; k < 8; k++) {
        float4 w = wr[k];
        float4 v0 = x0[k], v1 = x1[k], v2 = x2[k], v3 = x3[k];
        a0 += w.x * v0.x + w.y * v0.y + w.z * v0.z + w.w * v0.w;
        a1 += w.x * v1.x + w.y * v1.y + w.z * v1.z + w.w * v1.w;
        a2 += w.x * v2.x + w.y * v2.y + w.z * v2.z + w.w * v2.w;
        a3 += w.x * v3.x + w.y * v3.y + w.z * v3.z + w.w * v3.w;
    }
    a0 = warp_sum(a0); a1 = warp_sum(a1); a2 = warp_sum(a2); a3 = warp_sum(a3);
    if (lane < 4) {
        float a = (lane == 0) ? a0 : (lane == 1) ? a1 : (lane == 2) ? a2 : a3;
        r2f[lane * 1024 + d] = x1f[lane * 1024 + d] + b2[d] + a;
    }
}

__global__ __launch_bounds__(256) void k_gate(const float* __restrict__ rc,
                                              const float* __restrict__ gw,
                                              const float* __restrict__ gb,
                                              float* __restrict__ bw) {
    __shared__ __align__(16) float xs[4096];
    int tid = threadIdx.x;
#pragma unroll
    for (int i = 0; i < 16; i++) xs[i * 256 + tid] = rc[i * 256 + tid];
    __syncthreads();
    int wave = tid >> 6, lane = tid & 63;
    int u = blockIdx.x * 4 + wave;
    const float4* wr = (const float4*)(gw + (long)u * 1024) + lane * 4;
    const float4* x0 = (const float4*)xs + lane * 4;
    const float4* x1 = (const float4*)(xs + 1024) + lane * 4;
    const float4* x2 = (const float4*)(xs + 2048) + lane * 4;
    const float4* x3 = (const float4*)(xs + 3072) + lane * 4;
    float a0 = 0, a1 = 0, a2 = 0, a3 = 0;
#pragma unroll
    for (int k = 0; k < 4; k++) {
        float4 w = wr[k];
        float4 v0 = x0[k], v1 = x1[k], v2 = x2[k], v3 = x3[k];
        a0 += w.x * v0.x + w.y * v0.y + w.z * v0.z + w.w * v0.w;
        a1 += w.x * v1.x + w.y * v1.y + w.z * v1.z + w.w * v1.w;
        a2 += w.x * v2.x + w.y * v2.y + w.z * v2.z + w.w * v2.w;
        a3 += w.x * v3.x + w.y * v3.y + w.z * v3.z + w.w * v3.w;
    }
    a0 = warp_sum(a0); a1 = warp_sum(a1); a2 = warp_sum(a2); a3 = warp_sum(a3);
    if (lane == 0)
        bw[u] = 0.25f * (a0 + a1 + a2 + a3) + gb[u];
}

__global__ __launch_bounds__(256) void k_topk(const float* __restrict__ bw,
                                              const int* __restrict__ uids,
                                              const float* __restrict__ noise,
                                              float* __restrict__ out) {
    int tid = threadIdx.x;
    __shared__ float full[2000];
    __shared__ float sb[8];
    __shared__ float rv[256];
    __shared__ int ri[256];
    float s = 0.f, sq = 0.f;
    for (int u = tid; u < 2000; u += 256) {
        float v = bw[u];
        s += v; sq += v * v;
    }
    s = block_sum(s, sb); sq = block_sum(sq, sb + 4);
    float mean = s * (1.f / 2000.f);
    float sd = sqrtf(fmaxf(sq * (1.f / 2000.f) - mean * mean, 0.f));
    for (int i = tid; i < 2000; i += 256) full[i] = 0.f;
    __syncthreads();
    for (int i = tid; i < 2000; i += 256) {
        int u = uids[i];
        if (u >= 0 && u < 2000) full[u] = bw[i] + noise[i] * sd;
    }
    __syncthreads();
    for (int it = 0; it < 20; ++it) {
        float bv = -INFINITY;
        int bi = 0x7fffffff;
        for (int i = tid; i < 2000; i += 256) {
            float v = full[i];
            if (v > bv || (v == bv && i < bi)) { bv = v; bi = i; }
        }
        rv[tid] = bv; ri[tid] = bi;
        __syncthreads();
        for (int stride = 128; stride > 0; stride >>= 1) {
            if (tid < stride) {
                float v2 = rv[tid + stride]; int i2 = ri[tid + stride];
                if (v2 > rv[tid] || (v2 == rv[tid] && i2 < ri[tid])) { rv[tid] = v2; ri[tid] = i2; }
            }
            __syncthreads();
        }
        if (tid == 0) {
            out[1 + it] = rv[0];
            out[21 + it] = (float)ri[0];
            full[ri[0]] = -INFINITY;
        }
        __syncthreads();
    }
}

__global__ __launch_bounds__(256) void k_vt(const ushort_t* __restrict__ qkv,
                                            ushort_t* __restrict__ vt) {
    int zz = blockIdx.y, b = zz >> 3, h = zz & 7;
    int s0 = blockIdx.x * 64, tid = threadIdx.x;
    __shared__ ushort_t t[64][130];
#pragma unroll
    for (int r = 0; r < 32; r++) {
        int idx = r * 256 + tid;
        int sl = idx >> 7, d = idx & 127;
        t[sl][d] = qkv[((long)(b * 256 + s0 + sl)) * 3072 + 2048 + h * 128 + d];
    }
    __syncthreads();
#pragma unroll
    for (int r = 0; r < 32; r++) {
        int idx = r * 256 + tid;
        int d = idx >> 6, sl = idx & 63;
        vt[((long)(zz * 128 + d)) * 256 + s0 + sl] = t[sl][d];
    }
}

__global__ void k_softmax(const float* __restrict__ S, ushort_t* __restrict__ P) {
    long row = blockIdx.x;
    int lane = threadIdx.x;  // 64 threads
    const float* sr = S + row * 256;
    float v[4];
    float m = -INFINITY;
#pragma unroll
    for (int i = 0; i < 4; i++) {
        v[i] = sr[i * 64 + lane] * 0.08838834764831845f;
        m = fmaxf(m, v[i]);
    }
    m = warp_max(m);
    float s = 0.f;
#pragma unroll
    for (int i = 0; i < 4; i++) { v[i] = __expf(v[i] - m); s += v[i]; }
    s = warp_sum(s);
    float inv = 1.f / s;
#pragma unroll
    for (int i = 0; i < 4; i++) P[row * 256 + i * 64 + lane] = f2bf(v[i] * inv);
}

__global__ __launch_bounds__(256) void k_addln(const float* __restrict__ x,
                                               const float* __restrict__ y,
                                               const float* __restrict__ g,
                                               const float* __restrict__ b,
                                               float* __restrict__ xf,
                                               ushort_t* __restrict__ xb) {
    int row = blockIdx.x, tid = threadIdx.x;
    const float* xr = x + (long)row * 1024;
    const float* yr = y + (long)row * 1024;
    __shared__ float sb[8];
    float r[4], s = 0.f, sq = 0.f;
#pragma unroll
    for (int i = 0; i < 4; i++) {
        int d = i * 256 + tid;
        r[i] = xr[d] + yr[d];
        s += r[i]; sq += r[i] * r[i];
    }
    s = block_sum(s, sb); sq = block_sum(sq, sb + 4);
    float mean = s * (1.f / 1024.f);
    float rstd = rsqrtf(sq * (1.f / 1024.f) - mean * mean + 1e-5f);
#pragma unroll
    for (int i = 0; i < 4; i++) {
        int d = i * 256 + tid;
        float o = (r[i] - mean) * rstd * g[d] + b[d];
        xf[(long)row * 1024 + d] = o;
        xb[(long)row * 1024 + d] = f2bf(o);
    }
}

__global__ __launch_bounds__(256) void k_ce(const float* __restrict__ pm,
                                            const float* __restrict__ ps,
                                            const float* __restrict__ ll,
                                            const int* __restrict__ inputs,
                                            float* __restrict__ out) {
    const int NB = 393;
    long row = blockIdx.x;
    int tid = threadIdx.x;
    __shared__ float sb[8];
    float m = -INFINITY;
    for (int i = tid; i < NB; i += 256) m = fmaxf(m, pm[row * NB + i]);
    m = block_max(m, sb);
    float s = 0.f;
    for (int i = tid; i < NB; i += 256) s += ps[row * NB + i] * __expf(pm[row * NB + i] - m);
    s = block_sum(s, sb);
    if (tid == 0) {
        int lab = ((row & 255) == 255) ? -1 : inputs[row + 1];
        if (lab >= 0) atomicAdd(out, (m + logf(s) - ll[row]) * (1.0f / 1020.0f));
    }
}

// ---------------------------------------------------------------------------

extern "C" void kernel_launch(void* const* d_in, const int* in_sizes, int n_in,
                              void* d_out, int out_size, void* d_ws, size_t ws_size,
                              hipStream_t stream) {
    const int* inputs  = (const int*)d_in[0];
    const int* uids    = (const int*)d_in[1];
    const float* noise = (const float*)d_in[2];
    const float* resp  = (const float*)d_in[3];
    const float* emb   = (const float*)d_in[5];
    const float* r_Wqkv = (const float*)d_in[6];
    const float* r_bqkv = (const float*)d_in[7];
    const float* r_Wo = (const float*)d_in[8];
    const float* r_bo = (const float*)d_in[9];
    const float* r_W1 = (const float*)d_in[10];
    const float* r_b1 = (const float*)d_in[11];
    const float* r_W2 = (const float*)d_in[12];
    const float* r_b2 = (const float*)d_in[13];
    const float* r_ln1g = (const float*)d_in[14];
    const float* r_ln1b = (const float*)d_in[15];
    const float* r_ln2g = (const float*)d_in[16];
    const float* r_ln2b = (const float*)d_in[17];
    const float* e_Wqkv = (const float*)d_in[18];
    const float* e_bqkv = (const float*)d_in[19];
    const float* e_Wo = (const float*)d_in[20];
    const float* e_bo = (const float*)d_in[21];
    const float* e_W1 = (const float*)d_in[22];
    const float* e_b1 = (const float*)d_in[23];
    const float* e_W2 = (const float*)d_in[24];
    const float* e_b2 = (const float*)d_in[25];
    const float* e_ln1g = (const float*)d_in[26];
    const float* e_ln1b = (const float*)d_in[27];
    const float* e_ln2g = (const float*)d_in[28];
    const float* e_ln2b = (const float*)d_in[29];
    const float* dec_W = (const float*)d_in[30];
    const float* gate_W = (const float*)d_in[31];
    const float* gate_b = (const float*)d_in[32];
    float* out = (float*)d_out;
    (void)in_sizes; (void)n_in; (void)out_size; (void)ws_size;

    char* wp = (char*)d_ws;
    auto alloc = [&](size_t bytes) {
        char* p = wp;
        wp += (bytes + 255) & ~(size_t)255;
        return p;
    };
    ushort_t* wkv_hi = (ushort_t*)alloc(2097152ull * 2);   // r_Wqkv rows 1024..3071
    ushort_t* wkv_lo = (ushort_t*)alloc(2097152ull * 2);
    ushort_t* wq_e = (ushort_t*)alloc(6291456ull * 2);
    ushort_t* wo_e = (ushort_t*)alloc(2097152ull * 2);
    ushort_t* w1_e = (ushort_t*)alloc(4194304ull * 2);
    ushort_t* w2_e = (ushort_t*)alloc(4194304ull * 2);
    ushort_t* decb = (ushort_t*)alloc(51511296ull * 2);    // padded to 50304 rows
    ushort_t* h_hi = (ushort_t*)alloc(1048576ull * 2);
    ushort_t* h_lo = (ushort_t*)alloc(1048576ull * 2);
    float* qf = (float*)alloc(4096ull * 4);
    float* rkv = (float*)alloc(2097152ull * 4);            // [1024, 2048] k|v
    float* o_rt = (float*)alloc(4096ull * 4);
    float* rbuf = (float*)alloc(4096ull * 4);
    float* x1f = (float*)alloc(4096ull * 4);
    float* f1f = (float*)alloc(8192ull * 4);
    float* r2f = (float*)alloc(4096ull * 4);
    float* rc = (float*)alloc(4096ull * 4);
    float* bw = (float*)alloc(2000ull * 4);
    ushort_t* xb = (ushort_t*)alloc(1048576ull * 2);
    float* xf = (float*)alloc(1048576ull * 4);
    ushort_t* qkvb = (ushort_t*)alloc(3145728ull * 2);
    ushort_t* vt = (ushort_t*)alloc(1048576ull * 2);
    float* Sb = (float*)alloc(2097152ull * 4);
    ushort_t* Pb = (ushort_t*)alloc(2097152ull * 2);
    ushort_t* ob = (ushort_t*)alloc(1048576ull * 2);
    float* tmpf = (float*)alloc(1048576ull * 4);
    ushort_t* ff1b = (ushort_t*)alloc(2097152ull * 2);
    float* pm = (float*)alloc(1024ull * 393 * 4);
    float* ps = (float*)alloc(1024ull * 393 * 4);
    float* ll = (float*)alloc(1024ull * 4);

    auto gemm = [&](int epi, const ushort_t* A_, long lda_, long sA1_, long sA2_,
                    const ushort_t* B_, long ldb_, long sB1_, long sB2_,
                    void* C_, long ldc_, long sC1_, long sC2_,
                    const float* bias_, int accum_, int M_, int N_, int K_,
                    int batch_, int batch2_) {
        dim3 g((unsigned)(N_ / 128), (unsigned)(M_ / 128), (unsigned)batch_);
        switch (epi) {
        case 0: gemm_bt<0><<<g, 256, 0, stream>>>(A_, lda_, sA1_, sA2_, B_, ldb_, sB1_, sB2_, C_, ldc_, sC1_, sC2_, bias_, accum_, K_, batch2_); break;
        case 1: gemm_bt<1><<<g, 256, 0, stream>>>(A_, lda_, sA1_, sA2_, B_, ldb_, sB1_, sB2_, C_, ldc_, sC1_, sC2_, bias_, accum_, K_, batch2_); break;
        case 2: gemm_bt<2><<<g, 256, 0, stream>>>(A_, lda_, sA1_, sA2_, B_, ldb_, sB1_, sB2_, C_, ldc_, sC1_, sC2_, bias_, accum_, K_, batch2_); break;
        }
    };

    // ---- conversions ----
    k_convert_seg<<<17408, 256, 0, stream>>>(
        e_Wqkv, wq_e, 6291456L, e_Wo, wo_e, 2097152L, e_W1, w1_e, 4194304L,
        e_W2, w2_e, 4194304L, resp, xb, 1048576L);
    k_convert_pad<<<50304, 256, 0, stream>>>(dec_W, decb, 51464192L, 51511296L);
    k_convert2<<<2048, 256, 0, stream>>>(r_Wqkv + 1048576, wkv_hi, wkv_lo, 2097152L);
    k_gather2<<<1024, 256, 0, stream>>>(inputs, emb, h_hi, h_lo, out);

    // ---- routing path ----
    k_rq<<<256, 256, 0, stream>>>(inputs, emb, r_Wqkv, r_bqkv, qf);
    {
        dim3 g(16, 8);
        gemm_split<<<g, 256, 0, stream>>>(h_hi, h_lo, 1024, wkv_hi, wkv_lo, 1024,
                                          rkv, 2048, r_bqkv + 1024, 1024);
    }
    k_rattn<<<32, 256, 0, stream>>>(qf, rkv, o_rt);
    k_rwo<<<256, 256, 0, stream>>>(o_rt, inputs, emb, r_Wo, r_bo, rbuf);
    k_rln<<<4, 256, 0, stream>>>(rbuf, r_ln1g, r_ln1b, x1f, 1.0f);
    k_rff1<<<512, 256, 0, stream>>>(x1f, r_W1, r_b1, f1f);
    k_rff2<<<256, 256, 0, stream>>>(f1f, x1f, r_W2, r_b2, r2f);
    k_rln<<<4, 256, 0, stream>>>(r2f, r_ln2g, r_ln2b, rc, 32.0f);
    k_gate<<<500, 256, 0, stream>>>(rc, gate_W, gate_b, bw);
    k_topk<<<1, 256, 0, stream>>>(bw, uids, noise, out);

    // ---- main encoder (2 layers) ----
    for (int l = 0; l < 2; ++l) {
        gemm(1, xb, 1024, 0, 0, wq_e + (size_t)l * 3145728, 1024, 0, 0, qkvb, 3072, 0, 0,
             e_bqkv + l * 3072, 0, 1024, 3072, 1024, 1, 1);
        k_vt<<<dim3(4, 32), 256, 0, stream>>>(qkvb, vt);
        gemm(0, qkvb, 3072, 786432, 128, qkvb + 1024, 3072, 786432, 128, Sb, 256, 524288, 65536,
             nullptr, 0, 256, 256, 128, 32, 8);
        k_softmax<<<8192, 64, 0, stream>>>(Sb, Pb);
        gemm(1, Pb, 256, 524288, 65536, vt, 256, 262144, 32768, ob, 1024, 262144, 128,
             nullptr, 0, 256, 128, 256, 32, 8);
        gemm(0, ob, 1024, 0, 0, wo_e + (size_t)l * 1048576, 1024, 0, 0, tmpf, 1024, 0, 0,
             e_bo + l * 1024, 0, 1024, 1024, 1024, 1, 1);
        k_addln<<<1024, 256, 0, stream>>>((l == 0) ? resp : (const float*)xf, tmpf,
                                          e_ln1g + l * 1024, e_ln1b + l * 1024, xf, xb);
        gemm(2, xb, 1024, 0, 0, w1_e + (size_t)l * 2097152, 1024, 0, 0, ff1b, 2048, 0, 0,
             e_b1 + l * 2048, 0, 1024, 2048, 1024, 1, 1);
        gemm(0, ff1b, 2048, 0, 0, w2_e + (size_t)l * 2097152, 2048, 0, 0, tmpf, 1024, 0, 0,
             e_b2 + l * 1024, 0, 1024, 1024, 2048, 1, 1);
        k_addln<<<1024, 256, 0, stream>>>(xf, tmpf, e_ln2g + l * 1024, e_ln2b + l * 1024, xf, xb);
    }

    // ---- decoder + CE (logits never materialized) ----
    {
        dim3 g(393, 4);
        gemm_ce<<<g, 256, 0, stream>>>(xb, 1024, decb, 1024, 1024, 50258, inputs, pm, ps, ll);
    }
    k_ce<<<1024, 256, 0, stream>>>(pm, ps, ll, inputs, out);
}

// Round 4
// 1271.727 us; speedup vs baseline: 1.0882x; 1.0882x over previous
//
#include <hip/hip_runtime.h>

typedef unsigned short ushort_t;
typedef __bf16 bf16x8_t __attribute__((ext_vector_type(8)));
typedef float f32x4_t __attribute__((ext_vector_type(4)));

#define AS1(p) ((const __attribute__((address_space(1))) void*)(p))
#define AS3(p) ((__attribute__((address_space(3))) void*)(p))
#define DEVINL __device__ __forceinline__

DEVINL ushort_t f2bf(float f) {
    unsigned int u = __builtin_bit_cast(unsigned int, f);
    u += 0x7fffu + ((u >> 16) & 1u);
    return (ushort_t)(u >> 16);
}
DEVINL float bf2f(ushort_t h) {
    unsigned int u = ((unsigned int)h) << 16;
    return __builtin_bit_cast(float, u);
}

DEVINL float warp_sum(float v) {
#pragma unroll
    for (int o = 32; o > 0; o >>= 1) v += __shfl_xor(v, o);
    return v;
}
DEVINL float warp_max(float v) {
#pragma unroll
    for (int o = 32; o > 0; o >>= 1) v = fmaxf(v, __shfl_xor(v, o));
    return v;
}
DEVINL float block_sum(float v, float* sb) {
    v = warp_sum(v);
    int w = threadIdx.x >> 6;
    if ((threadIdx.x & 63) == 0) sb[w] = v;
    __syncthreads();
    v = sb[0] + sb[1] + sb[2] + sb[3];
    __syncthreads();
    return v;
}
DEVINL float block_max(float v, float* sb) {
    v = warp_max(v);
    int w = threadIdx.x >> 6;
    if ((threadIdx.x & 63) == 0) sb[w] = v;
    __syncthreads();
    v = fmaxf(fmaxf(sb[0], sb[1]), fmaxf(sb[2], sb[3]));
    __syncthreads();
    return v;
}

// ---------------------------------------------------------------------------
// NT GEMM: C[m,n] = sum_k A[m,k]*B[n,k], 128x128 tile, BK=32.
// EPI: 0 = fp32 out (+bias, +optional accumulate), 1 = bf16 (+bias),
//      2 = bf16 relu (+bias).
// ---------------------------------------------------------------------------
template <int EPI>
__global__ __launch_bounds__(256) void gemm_bt(
    const ushort_t* __restrict__ A, long lda, long sA1, long sA2,
    const ushort_t* __restrict__ B, long ldb, long sB1, long sB2,
    void* __restrict__ Cp, long ldc, long sC1, long sC2,
    const float* __restrict__ bias, int accum, int K, int batch2)
{
    __shared__ __align__(16) __bf16 As[128 * 32];
    __shared__ __align__(16) __bf16 Bs[128 * 32];

    const int tid = threadIdx.x;
    const int lane = tid & 63;
    const int wave = tid >> 6;
    const int wm = wave >> 1, wn = wave & 1;
    const int quad = lane >> 4, l16 = lane & 15;
    const long m0 = (long)blockIdx.y * 128;
    const long n0 = (long)blockIdx.x * 128;
    const int z = blockIdx.z;
    const int z1 = z / batch2, z2 = z % batch2;
    A += (long)z1 * sA1 + (long)z2 * sA2;
    B += (long)z1 * sB1 + (long)z2 * sB2;

    f32x4_t acc[4][4];
#pragma unroll
    for (int i = 0; i < 4; i++)
#pragma unroll
        for (int j = 0; j < 4; j++) {
            f32x4_t zv = {0.f, 0.f, 0.f, 0.f};
            acc[i][j] = zv;
        }

    const int ea = tid * 8;
    const int nkt = K >> 5;
    for (int kt = 0; kt < nkt; ++kt) {
        const int k0 = kt << 5;
#pragma unroll
        for (int inst = 0; inst < 2; ++inst) {
            int e = ea + inst * 2048;
            int row = e >> 5, kk = e & 31;
            __builtin_amdgcn_global_load_lds(AS1(A + (m0 + row) * lda + k0 + kk), AS3(As + e), 16, 0, 0);
            __builtin_amdgcn_global_load_lds(AS1(B + (n0 + row) * ldb + k0 + kk), AS3(Bs + e), 16, 0, 0);
        }
        __syncthreads();
        bf16x8_t af[4], bfr[4];
#pragma unroll
        for (int i = 0; i < 4; i++)
            af[i] = *(const bf16x8_t*)(As + (wm * 64 + i * 16 + l16) * 32 + quad * 8);
#pragma unroll
        for (int j = 0; j < 4; j++)
            bfr[j] = *(const bf16x8_t*)(Bs + (wn * 64 + j * 16 + l16) * 32 + quad * 8);
#pragma unroll
        for (int i = 0; i < 4; i++)
#pragma unroll
            for (int j = 0; j < 4; j++)
                acc[i][j] = __builtin_amdgcn_mfma_f32_16x16x32_bf16(af[i], bfr[j], acc[i][j], 0, 0, 0);
        __syncthreads();
    }

    if constexpr (EPI == 0) {
        float* C = (float*)Cp + (long)z1 * sC1 + (long)z2 * sC2;
#pragma unroll
        for (int i = 0; i < 4; i++)
#pragma unroll
            for (int reg = 0; reg < 4; reg++) {
                long row = m0 + wm * 64 + i * 16 + quad * 4 + reg;
#pragma unroll
                for (int j = 0; j < 4; j++) {
                    long col = n0 + wn * 64 + j * 16 + l16;
                    float v = acc[i][j][reg];
                    if (bias) v += bias[col];
                    long idx = row * ldc + col;
                    if (accum) v += C[idx];
                    C[idx] = v;
                }
            }
    } else {
        ushort_t* C = (ushort_t*)Cp + (long)z1 * sC1 + (long)z2 * sC2;
#pragma unroll
        for (int i = 0; i < 4; i++)
#pragma unroll
            for (int reg = 0; reg < 4; reg++) {
                long row = m0 + wm * 64 + i * 16 + quad * 4 + reg;
#pragma unroll
                for (int j = 0; j < 4; j++) {
                    long col = n0 + wn * 64 + j * 16 + l16;
                    float v = acc[i][j][reg];
                    if (bias) v += bias[col];
                    if constexpr (EPI == 2) v = fmaxf(v, 0.f);
                    C[row * ldc + col] = f2bf(v);
                }
            }
    }
}

// ---------------------------------------------------------------------------
// Split-precision NT GEMM (bf16x2): C = (Ah+Al)*(Bh+Bl)^T ~ AhBh + AhBl + AlBh
// fp32 out + bias. 128x128 tile.
// ---------------------------------------------------------------------------
__global__ __launch_bounds__(256) void gemm_split(
    const ushort_t* __restrict__ Ah, const ushort_t* __restrict__ Al, long lda,
    const ushort_t* __restrict__ Bh, const ushort_t* __restrict__ Bl, long ldb,
    float* __restrict__ C, long ldc, const float* __restrict__ bias, int K)
{
    __shared__ __align__(16) __bf16 Ahs[4096], Als[4096], Bhs[4096], Bls[4096];
    const int tid = threadIdx.x;
    const int lane = tid & 63;
    const int wave = tid >> 6;
    const int wm = wave >> 1, wn = wave & 1;
    const int quad = lane >> 4, l16 = lane & 15;
    const long m0 = (long)blockIdx.y * 128;
    const long n0 = (long)blockIdx.x * 128;

    f32x4_t acc[4][4];
#pragma unroll
    for (int i = 0; i < 4; i++)
#pragma unroll
        for (int j = 0; j < 4; j++) {
            f32x4_t zv = {0.f, 0.f, 0.f, 0.f};
            acc[i][j] = zv;
        }

    const int ea = tid * 8;
    const int nkt = K >> 5;
    for (int kt = 0; kt < nkt; ++kt) {
        const int k0 = kt << 5;
#pragma unroll
        for (int inst = 0; inst < 2; ++inst) {
            int e = ea + inst * 2048;
            int row = e >> 5, kk = e & 31;
            long ao = (m0 + row) * lda + k0 + kk;
            long bo = (n0 + row) * ldb + k0 + kk;
            __builtin_amdgcn_global_load_lds(AS1(Ah + ao), AS3(Ahs + e), 16, 0, 0);
            __builtin_amdgcn_global_load_lds(AS1(Al + ao), AS3(Als + e), 16, 0, 0);
            __builtin_amdgcn_global_load_lds(AS1(Bh + bo), AS3(Bhs + e), 16, 0, 0);
            __builtin_amdgcn_global_load_lds(AS1(Bl + bo), AS3(Bls + e), 16, 0, 0);
        }
        __syncthreads();
        bf16x8_t ah[4], al[4], bh[4], bl[4];
#pragma unroll
        for (int i = 0; i < 4; i++) {
            int off = (wm * 64 + i * 16 + l16) * 32 + quad * 8;
            ah[i] = *(const bf16x8_t*)(Ahs + off);
            al[i] = *(const bf16x8_t*)(Als + off);
        }
#pragma unroll
        for (int j = 0; j < 4; j++) {
            int off = (wn * 64 + j * 16 + l16) * 32 + quad * 8;
            bh[j] = *(const bf16x8_t*)(Bhs + off);
            bl[j] = *(const bf16x8_t*)(Bls + off);
        }
#pragma unroll
        for (int i = 0; i < 4; i++)
#pragma unroll
            for (int j = 0; j < 4; j++) {
                acc[i][j] = __builtin_amdgcn_mfma_f32_16x16x32_bf16(al[i], bh[j], acc[i][j], 0, 0, 0);
                acc[i][j] = __builtin_amdgcn_mfma_f32_16x16x32_bf16(ah[i], bl[j], acc[i][j], 0, 0, 0);
                acc[i][j] = __builtin_amdgcn_mfma_f32_16x16x32_bf16(ah[i], bh[j], acc[i][j], 0, 0, 0);
            }
        __syncthreads();
    }

#pragma unroll
    for (int i = 0; i < 4; i++)
#pragma unroll
        for (int reg = 0; reg < 4; reg++) {
            long row = m0 + wm * 64 + i * 16 + quad * 4 + reg;
#pragma unroll
            for (int j = 0; j < 4; j++) {
                long col = n0 + wn * 64 + j * 16 + l16;
                C[row * ldc + col] = acc[i][j][reg] + bias[col];
            }
        }
}

// ---------------------------------------------------------------------------
// Decoder CE GEMM: 128x128 tile, acc[4][4] (proven 76-VGPR / 30%-occ shape).
// Grid: x = m-tiles (8, FASTEST-varying for B-tile L2 reuse), y = n-tiles (393).
// Epilogue: per-(row, 64-col) partial max/sumexp + label-logit capture.
// ---------------------------------------------------------------------------
__global__ __launch_bounds__(256) void gemm_ce(
    const ushort_t* __restrict__ A, long lda,
    const ushort_t* __restrict__ B, long ldb,
    int K, int n_real, const int* __restrict__ inputs,
    float* __restrict__ part_m, float* __restrict__ part_s,
    float* __restrict__ label_logit)
{
    __shared__ __align__(16) __bf16 As[128 * 32];
    __shared__ __align__(16) __bf16 Bs[128 * 32];

    const int tid = threadIdx.x;
    const int lane = tid & 63;
    const int wave = tid >> 6;
    const int wm = wave >> 1, wn = wave & 1;
    const int quad = lane >> 4, l16 = lane & 15;
    const long m0 = (long)blockIdx.x * 128;   // m fastest
    const long n0 = (long)blockIdx.y * 128;

    f32x4_t acc[4][4];
#pragma unroll
    for (int i = 0; i < 4; i++)
#pragma unroll
        for (int j = 0; j < 4; j++) {
            f32x4_t zv = {0.f, 0.f, 0.f, 0.f};
            acc[i][j] = zv;
        }

    const int ea = tid * 8;
    const int nkt = K >> 5;
    for (int kt = 0; kt < nkt; ++kt) {
        const int k0 = kt << 5;
#pragma unroll
        for (int inst = 0; inst < 2; ++inst) {
            int e = ea + inst * 2048;
            int row = e >> 5, kk = e & 31;
            __builtin_amdgcn_global_load_lds(AS1(A + (m0 + row) * lda + k0 + kk), AS3(As + e), 16, 0, 0);
            __builtin_amdgcn_global_load_lds(AS1(B + (n0 + row) * ldb + k0 + kk), AS3(Bs + e), 16, 0, 0);
        }
        __syncthreads();
        bf16x8_t af[4], bfr[4];
#pragma unroll
        for (int i = 0; i < 4; i++)
            af[i] = *(const bf16x8_t*)(As + (wm * 64 + i * 16 + l16) * 32 + quad * 8);
#pragma unroll
        for (int j = 0; j < 4; j++)
            bfr[j] = *(const bf16x8_t*)(Bs + (wn * 64 + j * 16 + l16) * 32 + quad * 8);
#pragma unroll
        for (int i = 0; i < 4; i++)
#pragma unroll
            for (int j = 0; j < 4; j++)
                acc[i][j] = __builtin_amdgcn_mfma_f32_16x16x32_bf16(af[i], bfr[j], acc[i][j], 0, 0, 0);
        __syncthreads();
    }

#pragma unroll
    for (int i = 0; i < 4; i++) {
#pragma unroll
        for (int reg = 0; reg < 4; reg++) {
            long row = m0 + wm * 64 + i * 16 + quad * 4 + reg;
            int lab = ((row & 255) == 255) ? -1 : inputs[row + 1];
            float mx = -INFINITY;
#pragma unroll
            for (int j = 0; j < 4; j++) {
                long col = n0 + wn * 64 + j * 16 + l16;
                float v = acc[i][j][reg];
                if (col < n_real) mx = fmaxf(mx, v);
            }
#pragma unroll
            for (int o = 8; o > 0; o >>= 1) mx = fmaxf(mx, __shfl_xor(mx, o));
            float sm = 0.f;
#pragma unroll
            for (int j = 0; j < 4; j++) {
                long col = n0 + wn * 64 + j * 16 + l16;
                float v = acc[i][j][reg];
                if (col < n_real) sm += __expf(v - mx);
                if (col == lab) label_logit[row] = v;
            }
#pragma unroll
            for (int o = 8; o > 0; o >>= 1) sm += __shfl_xor(sm, o);
            if (l16 == 0) {
                long pidx = row * 786 + (long)blockIdx.y * 2 + wn;
                part_m[pidx] = mx;
                part_s[pidx] = sm;
            }
        }
    }
}

// ------------------------- small kernels -----------------------------------

__global__ __launch_bounds__(256) void k_convert_seg(
    const float* __restrict__ s0, ushort_t* __restrict__ d0, long n0,
    const float* __restrict__ s1, ushort_t* __restrict__ d1, long n1,
    const float* __restrict__ s2, ushort_t* __restrict__ d2, long n2,
    const float* __restrict__ s3, ushort_t* __restrict__ d3, long n3,
    const float* __restrict__ s4, ushort_t* __restrict__ d4, long n4)
{
    long i = ((long)blockIdx.x * 256 + threadIdx.x) * 4;
    const float* src; ushort_t* dst;
    if (i < n0) { src = s0; dst = d0; }
    else if ((i -= n0) < n1) { src = s1; dst = d1; }
    else if ((i -= n1) < n2) { src = s2; dst = d2; }
    else if ((i -= n2) < n3) { src = s3; dst = d3; }
    else if ((i -= n3) < n4) { src = s4; dst = d4; }
    else return;
    float4 v = *(const float4*)(src + i);
    dst[i + 0] = f2bf(v.x); dst[i + 1] = f2bf(v.y);
    dst[i + 2] = f2bf(v.z); dst[i + 3] = f2bf(v.w);
}

__global__ __launch_bounds__(256) void k_convert_pad(const float* __restrict__ src,
                                                     ushort_t* __restrict__ dst,
                                                     long n_src, long n_dst) {
    long i = ((long)blockIdx.x * 256 + threadIdx.x) * 4;
    if (i >= n_dst) return;
    if (i < n_src) {
        float4 v = *(const float4*)(src + i);
        dst[i + 0] = f2bf(v.x); dst[i + 1] = f2bf(v.y);
        dst[i + 2] = f2bf(v.z); dst[i + 3] = f2bf(v.w);
    } else {
        dst[i + 0] = 0; dst[i + 1] = 0; dst[i + 2] = 0; dst[i + 3] = 0;
    }
}

__global__ __launch_bounds__(256) void k_convert2(const float* __restrict__ src,
                                                  ushort_t* __restrict__ hi,
                                                  ushort_t* __restrict__ lo, long n) {
    long i = ((long)blockIdx.x * 256 + threadIdx.x) * 4;
    if (i >= n) return;
    float4 v = *(const float4*)(src + i);
    float vv[4] = {v.x, v.y, v.z, v.w};
#pragma unroll
    for (int j = 0; j < 4; j++) {
        ushort_t h = f2bf(vv[j]);
        hi[i + j] = h;
        lo[i + j] = f2bf(vv[j] - bf2f(h));
    }
}

__global__ __launch_bounds__(256) void k_gather2(const int* __restrict__ inputs,
                                                 const float* __restrict__ emb,
                                                 ushort_t* __restrict__ hi,
                                                 ushort_t* __restrict__ lo,
                                                 float* __restrict__ loss_out) {
    int t = blockIdx.x, tid = threadIdx.x;
    if (t == 0 && tid == 0) loss_out[0] = 0.f;
    long row = inputs[t];
    float4 v = *(const float4*)(emb + row * 1024 + tid * 4);
    long base = (long)t * 1024 + tid * 4;
    float vv[4] = {v.x, v.y, v.z, v.w};
#pragma unroll
    for (int j = 0; j < 4; j++) {
        ushort_t h = f2bf(vv[j]);
        hi[base + j] = h;
        lo[base + j] = f2bf(vv[j] - bf2f(h));
    }
}

// exact fp32 Q projection for the 4 last-position tokens: one wave per dim
__global__ __launch_bounds__(256) void k_rq(
    const int* __restrict__ inputs, const float* __restrict__ emb,
    const float* __restrict__ Wq, const float* __restrict__ bq,
    float* __restrict__ qf)
{
    __shared__ __align__(16) float xs[4096];
    int tid = threadIdx.x;
#pragma unroll
    for (int b2 = 0; b2 < 4; b2++) {
        long tok = inputs[b2 * 256 + 255];
        *(float4*)(xs + b2 * 1024 + tid * 4) = *(const float4*)(emb + tok * 1024 + tid * 4);
    }
    __syncthreads();
    int wave = tid >> 6, lane = tid & 63;
    int d = blockIdx.x * 4 + wave;
    const float4* wr = (const float4*)(Wq + (long)d * 1024) + lane * 4;
    const float4* x0 = (const float4*)xs + lane * 4;
    const float4* x1 = (const float4*)(xs + 1024) + lane * 4;
    const float4* x2 = (const float4*)(xs + 2048) + lane * 4;
    const float4* x3 = (const float4*)(xs + 3072) + lane * 4;
    float a0 = 0, a1 = 0, a2 = 0, a3 = 0;
#pragma unroll
    for (int k = 0; k < 4; k++) {
        float4 w = wr[k];
        float4 v0 = x0[k], v1 = x1[k], v2 = x2[k], v3 = x3[k];
        a0 += w.x * v0.x + w.y * v0.y + w.z * v0.z + w.w * v0.w;
        a1 += w.x * v1.x + w.y * v1.y + w.z * v1.z + w.w * v1.w;
        a2 += w.x * v2.x + w.y * v2.y + w.z * v2.z + w.w * v2.w;
        a3 += w.x * v3.x + w.y * v3.y + w.z * v3.z + w.w * v3.w;
    }
    a0 = warp_sum(a0); a1 = warp_sum(a1); a2 = warp_sum(a2); a3 = warp_sum(a3);
    if (lane < 4) {
        float a = (lane == 0) ? a0 : (lane == 1) ? a1 : (lane == 2) ? a2 : a3;
        qf[lane * 1024 + d] = a + bq[d];
    }
}

// routing attention, last query only; kv layout [B*S, 2048] (k | v)
__global__ __launch_bounds__(256) void k_rattn(const float* __restrict__ qf,
                                               const float* __restrict__ kv,
                                               float* __restrict__ o_rt) {
    int zz = blockIdx.x, b = zz >> 3, h = zz & 7, tid = threadIdx.x;
    __shared__ __align__(16) float q[128];
    __shared__ float p[256];
    __shared__ float sb[8];
    if (tid < 128) q[tid] = qf[b * 1024 + h * 128 + tid];
    __syncthreads();
    const float4* q4 = (const float4*)q;
    const float4* kr = (const float4*)(kv + ((long)(b * 256 + tid)) * 2048 + h * 128);
    float a = 0.f;
#pragma unroll 8
    for (int k = 0; k < 32; k++) {
        float4 wv = kr[k], xv = q4[k];
        a += wv.x * xv.x + wv.y * xv.y + wv.z * xv.z + wv.w * xv.w;
    }
    a *= 0.08838834764831845f;
    float m = block_max(a, sb);
    float e = __expf(a - m);
    float ssum = block_sum(e, sb);
    p[tid] = e / ssum;
    __syncthreads();
    if (tid < 128) {
        float acc = 0.f;
        const float* vb = kv + (long)b * 256 * 2048 + 1024 + h * 128 + tid;
        for (int s = 0; s < 256; s++) acc += p[s] * vb[(long)s * 2048];
        o_rt[b * 1024 + h * 128 + tid] = acc;
    }
}

// r[b][d] = emb[tok_b][d] + bo[d] + dot(Wo[d,:], o_rt[b,:])
__global__ __launch_bounds__(256) void k_rwo(
    const float* __restrict__ o_rt, const int* __restrict__ inputs,
    const float* __restrict__ emb, const float* __restrict__ Wo,
    const float* __restrict__ bo, float* __restrict__ rbuf)
{
    __shared__ __align__(16) float xs[4096];
    int tid = threadIdx.x;
#pragma unroll
    for (int i = 0; i < 16; i++) xs[i * 256 + tid] = o_rt[i * 256 + tid];
    __syncthreads();
    int wave = tid >> 6, lane = tid & 63;
    int d = blockIdx.x * 4 + wave;
    const float4* wr = (const float4*)(Wo + (long)d * 1024) + lane * 4;
    const float4* x0 = (const float4*)xs + lane * 4;
    const float4* x1 = (const float4*)(xs + 1024) + lane * 4;
    const float4* x2 = (const float4*)(xs + 2048) + lane * 4;
    const float4* x3 = (const float4*)(xs + 3072) + lane * 4;
    float a0 = 0, a1 = 0, a2 = 0, a3 = 0;
#pragma unroll
    for (int k = 0; k < 4; k++) {
        float4 w = wr[k];
        float4 v0 = x0[k], v1 = x1[k], v2 = x2[k], v3 = x3[k];
        a0 += w.x * v0.x + w.y * v0.y + w.z * v0.z + w.w * v0.w;
        a1 += w.x * v1.x + w.y * v1.y + w.z * v1.z + w.w * v1.w;
        a2 += w.x * v2.x + w.y * v2.y + w.z * v2.z + w.w * v2.w;
        a3 += w.x * v3.x + w.y * v3.y + w.z * v3.z + w.w * v3.w;
    }
    a0 = warp_sum(a0); a1 = warp_sum(a1); a2 = warp_sum(a2); a3 = warp_sum(a3);
    if (lane < 4) {
        float a = (lane == 0) ? a0 : (lane == 1) ? a1 : (lane == 2) ? a2 : a3;
        long tok = inputs[lane * 256 + 255];
        rbuf[lane * 1024 + d] = emb[tok * 1024 + d] + bo[d] + a;
    }
}

__global__ __launch_bounds__(256) void k_rln(const float* __restrict__ r,
                                             const float* __restrict__ g,
                                             const float* __restrict__ be,
                                             float* __restrict__ outp, float scale) {
    int row = blockIdx.x, tid = threadIdx.x;
    __shared__ float sb[8];
    const float* rr = r + (long)row * 1024;
    float v[4], s = 0.f, sq = 0.f;
#pragma unroll
    for (int i = 0; i < 4; i++) {
        v[i] = rr[i * 256 + tid];
        s += v[i]; sq += v[i] * v[i];
    }
    s = block_sum(s, sb); sq = block_sum(sq, sb + 4);
    float mean = s * (1.f / 1024.f);
    float rstd = rsqrtf(sq * (1.f / 1024.f) - mean * mean + 1e-5f);
#pragma unroll
    for (int i = 0; i < 4; i++) {
        int d = i * 256 + tid;
        outp[(long)row * 1024 + d] = ((v[i] - mean) * rstd * g[d] + be[d]) * scale;
    }
}

__global__ __launch_bounds__(256) void k_rff1(
    const float* __restrict__ x1f, const float* __restrict__ W1,
    const float* __restrict__ b1, float* __restrict__ f1f)
{
    __shared__ __align__(16) float xs[4096];
    int tid = threadIdx.x;
#pragma unroll
    for (int i = 0; i < 16; i++) xs[i * 256 + tid] = x1f[i * 256 + tid];
    __syncthreads();
    int wave = tid >> 6, lane = tid & 63;
    int j = blockIdx.x * 4 + wave;
    const float4* wr = (const float4*)(W1 + (long)j * 1024) + lane * 4;
    const float4* x0 = (const float4*)xs + lane * 4;
    const float4* x1 = (const float4*)(xs + 1024) + lane * 4;
    const float4* x2 = (const float4*)(xs + 2048) + lane * 4;
    const float4* x3 = (const float4*)(xs + 3072) + lane * 4;
    float a0 = 0, a1 = 0, a2 = 0, a3 = 0;
#pragma unroll
    for (int k = 0; k < 4; k++) {
        float4 w = wr[k];
        float4 v0 = x0[k], v1 = x1[k], v2 = x2[k], v3 = x3[k];
        a0 += w.x * v0.x + w.y * v0.y + w.z * v0.z + w.w * v0.w;
        a1 += w.x * v1.x + w.y * v1.y + w.z * v1.z + w.w * v1.w;
        a2 += w.x * v2.x + w.y * v2.y + w.z * v2.z + w.w * v2.w;
        a3 += w.x * v3.x + w.y * v3.y + w.z * v3.z + w.w * v3.w;
    }
    a0 = warp_sum(a0); a1 = warp_sum(a1); a2 = warp_sum(a2); a3 = warp_sum(a3);
    if (lane < 4) {
        float a = (lane == 0) ? a0 : (lane == 1) ? a1 : (lane == 2) ? a2 : a3;
        f1f[lane * 2048 + j] = fmaxf(b1[j] + a, 0.f);
    }
}

__global__ __launch_bounds__(256) void k_rff2(
    const float* __restrict__ f1f, const float* __restrict__ x1f,
    const float* __restrict__ W2, const float* __restrict__ b2,
    float* __restrict__ r2f)
{
    __shared__ __align__(16) float xs[8192];
    int tid = threadIdx.x;
#pragma unroll
    for (int i = 0; i < 32; i++) xs[i * 256 + tid] = f1f[i * 256 + tid];
    __syncthreads();
    int wave = tid >> 6, lane = tid & 63;
    int d = blockIdx.x * 4 + wave;
    const float4* wr = (const float4*)(W2 + (long)d * 2048) + lane * 8;
    const float4* x0 = (const float4*)xs + lane * 8;
    const float4* x1 = (const float4*)(xs + 2048) + lane * 8;
    const float4* x2 = (const float4*)(xs + 4096) + lane * 8;
    const float4* x3 = (const float4*)(xs + 6144) + lane * 8;
    float a0 = 0, a1 = 0, a2 = 0, a3 = 0;
#pragma unroll
    for (int k = 0; k < 8; k++) {
        float4 w = wr[k];
        float4 v0 = x0[k], v1 = x1[k], v2 = x2[k], v3 = x3[k];
        a0 += w.x * v0.x + w.y * v0.y + w.z * v0.z + w.w * v0.w;
        a1 += w.x * v1.x + w.y * v1.y + w.z * v1.z + w.w * v1.w;
        a2 += w.x * v2.x + w.y * v2.y + w.z * v2.z + w.w * v2.w;
        a3 += w.x * v3.x + w.y * v3.y + w.z * v3.z + w.w * v3.w;
    }
    a0 = warp_sum(a0); a1 = warp_sum(a1); a2 = warp_sum(a2); a3 = warp_sum(a3);
    if (lane < 4) {
        float a = (lane == 0) ? a0 : (lane == 1) ? a1 : (lane == 2) ? a2 : a3;
        r2f[lane * 1024 + d] = x1f[lane * 1024 + d] + b2[d] + a;
    }
}

__global__ __launch_bounds__(256) void k_gate(const float* __restrict__ rc,
                                              const float* __restrict__ gw,
                                              const float* __restrict__ gb,
                                              float* __restrict__ bw) {
    __shared__ __align__(16) float xs[4096];
    int tid = threadIdx.x;
#pragma unroll
    for (int i = 0; i < 16; i++) xs[i * 256 + tid] = rc[i * 256 + tid];
    __syncthreads();
    int wave = tid >> 6, lane = tid & 63;
    int u = blockIdx.x * 4 + wave;
    const float4* wr = (const float4*)(gw + (long)u * 1024) + lane * 4;
    const float4* x0 = (const float4*)xs + lane * 4;
    const float4* x1 = (const float4*)(xs + 1024) + lane * 4;
    const float4* x2 = (const float4*)(xs + 2048) + lane * 4;
    const float4* x3 = (const float4*)(xs + 3072) + lane * 4;
    float a0 = 0, a1 = 0, a2 = 0, a3 = 0;
#pragma unroll
    for (int k = 0; k < 4; k++) {
        float4 w = wr[k];
        float4 v0 = x0[k], v1 = x1[k], v2 = x2[k], v3 = x3[k];
        a0 += w.x * v0.x + w.y * v0.y + w.z * v0.z + w.w * v0.w;
        a1 += w.x * v1.x + w.y * v1.y + w.z * v1.z + w.w * v1.w;
        a2 += w.x * v2.x + w.y * v2.y + w.z * v2.z + w.w * v2.w;
        a3 += w.x * v3.x + w.y * v3.y + w.z * v3.z + w.w * v3.w;
    }
    a0 = warp_sum(a0); a1 = warp_sum(a1); a2 = warp_sum(a2); a3 = warp_sum(a3);
    if (lane == 0)
        bw[u] = 0.25f * (a0 + a1 + a2 + a3) + gb[u];
}

__global__ __launch_bounds__(256) void k_topk(const float* __restrict__ bw,
                                              const int* __restrict__ uids,
                                              const float* __restrict__ noise,
                                              float* __restrict__ out) {
    int tid = threadIdx.x;
    __shared__ float full[2000];
    __shared__ float sb[8];
    __shared__ float rv[256];
    __shared__ int ri[256];
    float s = 0.f, sq = 0.f;
    for (int u = tid; u < 2000; u += 256) {
        float v = bw[u];
        s += v; sq += v * v;
    }
    s = block_sum(s, sb); sq = block_sum(sq, sb + 4);
    float mean = s * (1.f / 2000.f);
    float sd = sqrtf(fmaxf(sq * (1.f / 2000.f) - mean * mean, 0.f));
    for (int i = tid; i < 2000; i += 256) full[i] = 0.f;
    __syncthreads();
    for (int i = tid; i < 2000; i += 256) {
        int u = uids[i];
        if (u >= 0 && u < 2000) full[u] = bw[i] + noise[i] * sd;
    }
    __syncthreads();
    for (int it = 0; it < 20; ++it) {
        float bv = -INFINITY;
        int bi = 0x7fffffff;
        for (int i = tid; i < 2000; i += 256) {
            float v = full[i];
            if (v > bv || (v == bv && i < bi)) { bv = v; bi = i; }
        }
        rv[tid] = bv; ri[tid] = bi;
        __syncthreads();
        for (int stride = 128; stride > 0; stride >>= 1) {
            if (tid < stride) {
                float v2 = rv[tid + stride]; int i2 = ri[tid + stride];
                if (v2 > rv[tid] || (v2 == rv[tid] && i2 < ri[tid])) { rv[tid] = v2; ri[tid] = i2; }
            }
            __syncthreads();
        }
        if (tid == 0) {
            out[1 + it] = rv[0];
            out[21 + it] = (float)ri[0];
            full[ri[0]] = -INFINITY;
        }
        __syncthreads();
    }
}

__global__ __launch_bounds__(256) void k_vt(const ushort_t* __restrict__ qkv,
                                            ushort_t* __restrict__ vt) {
    int zz = blockIdx.y, b = zz >> 3, h = zz & 7;
    int s0 = blockIdx.x * 64, tid = threadIdx.x;
    __shared__ ushort_t t[64][130];
#pragma unroll
    for (int r = 0; r < 32; r++) {
        int idx = r * 256 + tid;
        int sl = idx >> 7, d = idx & 127;
        t[sl][d] = qkv[((long)(b * 256 + s0 + sl)) * 3072 + 2048 + h * 128 + d];
    }
    __syncthreads();
#pragma unroll
    for (int r = 0; r < 32; r++) {
        int idx = r * 256 + tid;
        int d = idx >> 6, sl = idx & 63;
        vt[((long)(zz * 128 + d)) * 256 + s0 + sl] = t[sl][d];
    }
}

__global__ void k_softmax(const float* __restrict__ S, ushort_t* __restrict__ P) {
    long row = blockIdx.x;
    int lane = threadIdx.x;  // 64 threads
    const float* sr = S + row * 256;
    float v[4];
    float m = -INFINITY;
#pragma unroll
    for (int i = 0; i < 4; i++) {
        v[i] = sr[i * 64 + lane] * 0.08838834764831845f;
        m = fmaxf(m, v[i]);
    }
    m = warp_max(m);
    float s = 0.f;
#pragma unroll
    for (int i = 0; i < 4; i++) { v[i] = __expf(v[i] - m); s += v[i]; }
    s = warp_sum(s);
    float inv = 1.f / s;
#pragma unroll
    for (int i = 0; i < 4; i++) P[row * 256 + i * 64 + lane] = f2bf(v[i] * inv);
}

__global__ __launch_bounds__(256) void k_addln(const float* __restrict__ x,
                                               const float* __restrict__ y,
                                               const float* __restrict__ g,
                                               const float* __restrict__ b,
                                               float* __restrict__ xf,
                                               ushort_t* __restrict__ xb) {
    int row = blockIdx.x, tid = threadIdx.x;
    const float* xr = x + (long)row * 1024;
    const float* yr = y + (long)row * 1024;
    __shared__ float sb[8];
    float r[4], s = 0.f, sq = 0.f;
#pragma unroll
    for (int i = 0; i < 4; i++) {
        int d = i * 256 + tid;
        r[i] = xr[d] + yr[d];
        s += r[i]; sq += r[i] * r[i];
    }
    s = block_sum(s, sb); sq = block_sum(sq, sb + 4);
    float mean = s * (1.f / 1024.f);
    float rstd = rsqrtf(sq * (1.f / 1024.f) - mean * mean + 1e-5f);
#pragma unroll
    for (int i = 0; i < 4; i++) {
        int d = i * 256 + tid;
        float o = (r[i] - mean) * rstd * g[d] + b[d];
        xf[(long)row * 1024 + d] = o;
        xb[(long)row * 1024 + d] = f2bf(o);
    }
}

__global__ __launch_bounds__(256) void k_ce(const float* __restrict__ pm,
                                            const float* __restrict__ ps,
                                            const float* __restrict__ ll,
                                            const int* __restrict__ inputs,
                                            float* __restrict__ out) {
    const int NB = 786;
    long row = blockIdx.x;
    int tid = threadIdx.x;
    __shared__ float sb[8];
    float m = -INFINITY;
    for (int i = tid; i < NB; i += 256) m = fmaxf(m, pm[row * NB + i]);
    m = block_max(m, sb);
    float s = 0.f;
    for (int i = tid; i < NB; i += 256) s += ps[row * NB + i] * __expf(pm[row * NB + i] - m);
    s = block_sum(s, sb);
    if (tid == 0) {
        int lab = ((row & 255) == 255) ? -1 : inputs[row + 1];
        if (lab >= 0) atomicAdd(out, (m + logf(s) - ll[row]) * (1.0f / 1020.0f));
    }
}

// ---------------------------------------------------------------------------

extern "C" void kernel_launch(void* const* d_in, const int* in_sizes, int n_in,
                              void* d_out, int out_size, void* d_ws, size_t ws_size,
                              hipStream_t stream) {
    const int* inputs  = (const int*)d_in[0];
    const int* uids    = (const int*)d_in[1];
    const float* noise = (const float*)d_in[2];
    const float* resp  = (const float*)d_in[3];
    const float* emb   = (const float*)d_in[5];
    const float* r_Wqkv = (const float*)d_in[6];
    const float* r_bqkv = (const float*)d_in[7];
    const float* r_Wo = (const float*)d_in[8];
    const float* r_bo = (const float*)d_in[9];
    const float* r_W1 = (const float*)d_in[10];
    const float* r_b1 = (const float*)d_in[11];
    const float* r_W2 = (const float*)d_in[12];
    const float* r_b2 = (const float*)d_in[13];
    const float* r_ln1g = (const float*)d_in[14];
    const float* r_ln1b = (const float*)d_in[15];
    const float* r_ln2g = (const float*)d_in[16];
    const float* r_ln2b = (const float*)d_in[17];
    const float* e_Wqkv = (const float*)d_in[18];
    const float* e_bqkv = (const float*)d_in[19];
    const float* e_Wo = (const float*)d_in[20];
    const float* e_bo = (const float*)d_in[21];
    const float* e_W1 = (const float*)d_in[22];
    const float* e_b1 = (const float*)d_in[23];
    const float* e_W2 = (const float*)d_in[24];
    const float* e_b2 = (const float*)d_in[25];
    const float* e_ln1g = (const float*)d_in[26];
    const float* e_ln1b = (const float*)d_in[27];
    const float* e_ln2g = (const float*)d_in[28];
    const float* e_ln2b = (const float*)d_in[29];
    const float* dec_W = (const float*)d_in[30];
    const float* gate_W = (const float*)d_in[31];
    const float* gate_b = (const float*)d_in[32];
    float* out = (float*)d_out;
    (void)in_sizes; (void)n_in; (void)out_size; (void)ws_size;

    char* wp = (char*)d_ws;
    auto alloc = [&](size_t bytes) {
        char* p = wp;
        wp += (bytes + 255) & ~(size_t)255;
        return p;
    };
    ushort_t* wkv_hi = (ushort_t*)alloc(2097152ull * 2);   // r_Wqkv rows 1024..3071
    ushort_t* wkv_lo = (ushort_t*)alloc(2097152ull * 2);
    ushort_t* wq_e = (ushort_t*)alloc(6291456ull * 2);
    ushort_t* wo_e = (ushort_t*)alloc(2097152ull * 2);
    ushort_t* w1_e = (ushort_t*)alloc(4194304ull * 2);
    ushort_t* w2_e = (ushort_t*)alloc(4194304ull * 2);
    ushort_t* decb = (ushort_t*)alloc(51511296ull * 2);    // padded to 50304 rows
    ushort_t* h_hi = (ushort_t*)alloc(1048576ull * 2);
    ushort_t* h_lo = (ushort_t*)alloc(1048576ull * 2);
    float* qf = (float*)alloc(4096ull * 4);
    float* rkv = (float*)alloc(2097152ull * 4);            // [1024, 2048] k|v
    float* o_rt = (float*)alloc(4096ull * 4);
    float* rbuf = (float*)alloc(4096ull * 4);
    float* x1f = (float*)alloc(4096ull * 4);
    float* f1f = (float*)alloc(8192ull * 4);
    float* r2f = (float*)alloc(4096ull * 4);
    float* rc = (float*)alloc(4096ull * 4);
    float* bw = (float*)alloc(2000ull * 4);
    ushort_t* xb = (ushort_t*)alloc(1048576ull * 2);
    float* xf = (float*)alloc(1048576ull * 4);
    ushort_t* qkvb = (ushort_t*)alloc(3145728ull * 2);
    ushort_t* vt = (ushort_t*)alloc(1048576ull * 2);
    float* Sb = (float*)alloc(2097152ull * 4);
    ushort_t* Pb = (ushort_t*)alloc(2097152ull * 2);
    ushort_t* ob = (ushort_t*)alloc(1048576ull * 2);
    float* tmpf = (float*)alloc(1048576ull * 4);
    ushort_t* ff1b = (ushort_t*)alloc(2097152ull * 2);
    float* pm = (float*)alloc(1024ull * 786 * 4);
    float* ps = (float*)alloc(1024ull * 786 * 4);
    float* ll = (float*)alloc(1024ull * 4);

    auto gemm = [&](int epi, const ushort_t* A_, long lda_, long sA1_, long sA2_,
                    const ushort_t* B_, long ldb_, long sB1_, long sB2_,
                    void* C_, long ldc_, long sC1_, long sC2_,
                    const float* bias_, int accum_, int M_, int N_, int K_,
                    int batch_, int batch2_) {
        dim3 g((unsigned)(N_ / 128), (unsigned)(M_ / 128), (unsigned)batch_);
        switch (epi) {
        case 0: gemm_bt<0><<<g, 256, 0, stream>>>(A_, lda_, sA1_, sA2_, B_, ldb_, sB1_, sB2_, C_, ldc_, sC1_, sC2_, bias_, accum_, K_, batch2_); break;
        case 1: gemm_bt<1><<<g, 256, 0, stream>>>(A_, lda_, sA1_, sA2_, B_, ldb_, sB1_, sB2_, C_, ldc_, sC1_, sC2_, bias_, accum_, K_, batch2_); break;
        case 2: gemm_bt<2><<<g, 256, 0, stream>>>(A_, lda_, sA1_, sA2_, B_, ldb_, sB1_, sB2_, C_, ldc_, sC1_, sC2_, bias_, accum_, K_, batch2_); break;
        }
    };

    // ---- conversions ----
    k_convert_seg<<<17408, 256, 0, stream>>>(
        e_Wqkv, wq_e, 6291456L, e_Wo, wo_e, 2097152L, e_W1, w1_e, 4194304L,
        e_W2, w2_e, 4194304L, resp, xb, 1048576L);
    k_convert_pad<<<50304, 256, 0, stream>>>(dec_W, decb, 51464192L, 51511296L);
    k_convert2<<<2048, 256, 0, stream>>>(r_Wqkv + 1048576, wkv_hi, wkv_lo, 2097152L);
    k_gather2<<<1024, 256, 0, stream>>>(inputs, emb, h_hi, h_lo, out);

    // ---- routing path ----
    k_rq<<<256, 256, 0, stream>>>(inputs, emb, r_Wqkv, r_bqkv, qf);
    {
        dim3 g(16, 8);
        gemm_split<<<g, 256, 0, stream>>>(h_hi, h_lo, 1024, wkv_hi, wkv_lo, 1024,
                                          rkv, 2048, r_bqkv + 1024, 1024);
    }
    k_rattn<<<32, 256, 0, stream>>>(qf, rkv, o_rt);
    k_rwo<<<256, 256, 0, stream>>>(o_rt, inputs, emb, r_Wo, r_bo, rbuf);
    k_rln<<<4, 256, 0, stream>>>(rbuf, r_ln1g, r_ln1b, x1f, 1.0f);
    k_rff1<<<512, 256, 0, stream>>>(x1f, r_W1, r_b1, f1f);
    k_rff2<<<256, 256, 0, stream>>>(f1f, x1f, r_W2, r_b2, r2f);
    k_rln<<<4, 256, 0, stream>>>(r2f, r_ln2g, r_ln2b, rc, 32.0f);
    k_gate<<<500, 256, 0, stream>>>(rc, gate_W, gate_b, bw);
    k_topk<<<1, 256, 0, stream>>>(bw, uids, noise, out);

    // ---- main encoder (2 layers) ----
    for (int l = 0; l < 2; ++l) {
        gemm(1, xb, 1024, 0, 0, wq_e + (size_t)l * 3145728, 1024, 0, 0, qkvb, 3072, 0, 0,
             e_bqkv + l * 3072, 0, 1024, 3072, 1024, 1, 1);
        k_vt<<<dim3(4, 32), 256, 0, stream>>>(qkvb, vt);
        gemm(0, qkvb, 3072, 786432, 128, qkvb + 1024, 3072, 786432, 128, Sb, 256, 524288, 65536,
             nullptr, 0, 256, 256, 128, 32, 8);
        k_softmax<<<8192, 64, 0, stream>>>(Sb, Pb);
        gemm(1, Pb, 256, 524288, 65536, vt, 256, 262144, 32768, ob, 1024, 262144, 128,
             nullptr, 0, 256, 128, 256, 32, 8);
        gemm(0, ob, 1024, 0, 0, wo_e + (size_t)l * 1048576, 1024, 0, 0, tmpf, 1024, 0, 0,
             e_bo + l * 1024, 0, 1024, 1024, 1024, 1, 1);
        k_addln<<<1024, 256, 0, stream>>>((l == 0) ? resp : (const float*)xf, tmpf,
                                          e_ln1g + l * 1024, e_ln1b + l * 1024, xf, xb);
        gemm(2, xb, 1024, 0, 0, w1_e + (size_t)l * 2097152, 1024, 0, 0, ff1b, 2048, 0, 0,
             e_b1 + l * 2048, 0, 1024, 2048, 1024, 1, 1);
        gemm(0, ff1b, 2048, 0, 0, w2_e + (size_t)l * 2097152, 2048, 0, 0, tmpf, 1024, 0, 0,
             e_b2 + l * 1024, 0, 1024, 1024, 2048, 1, 1);
        k_addln<<<1024, 256, 0, stream>>>(xf, tmpf, e_ln2g + l * 1024, e_ln2b + l * 1024, xf, xb);
    }

    // ---- decoder + CE (logits never materialized) ----
    {
        dim3 g(8, 393);   // m fastest: 8 consecutive blocks share one B tile
        gemm_ce<<<g, 256, 0, stream>>>(xb, 1024, decb, 1024, 1024, 50258, inputs, pm, ps, ll);
    }
    k_ce<<<1024, 256, 0, stream>>>(pm, ps, ll, inputs, out);
}